// Round 2
// baseline (249.146 us; speedup 1.0000x reference)
//
#include <hip/hip_runtime.h>
#include <hip/hip_bf16.h>

#define BCNT 128
#define NNODE 64
#define HDIM 256
#define DDIM 128
#define KNEI 8

// ---- GEMM tile params ----
#define BM 64
#define BN 64
#define BK 16

// h[b,n,o] = X @ W1[n] + b1[n]; X = obs (KDIM=256) or concat(obs,act) (KDIM=512)
template<int KDIM>
__global__ __launch_bounds__(256) void mlp1_gemm(
    const float* __restrict__ obs, const float* __restrict__ act,
    const float* __restrict__ W1, const float* __restrict__ b1,
    float* __restrict__ h)
{
    const int n  = blockIdx.x;
    const int bm = blockIdx.y * BM;
    const int bn = blockIdx.z * BN;
    const int tid = threadIdx.x;
    const int tx = tid & 15, ty = tid >> 4;

    __shared__ float As[BK][BM + 4];   // As[k][m], row stride 272B (16B-aligned)
    __shared__ float Bs[BK][BN + 4];   // Bs[k][n], row stride 272B (16B-aligned)

    const float* Wn = W1 + (size_t)n * KDIM * HDIM;
    float acc[4][4] = {};

    for (int k0 = 0; k0 < KDIM; k0 += BK) {
        // X tile: 64 rows x 16 cols
        {
            const float* src = obs; int kb = k0;
            if (KDIM > HDIM && k0 >= HDIM) { src = act; kb = k0 - HDIM; }
            int r = tid >> 2;            // 0..63
            int c = (tid & 3) * 4;       // 0,4,8,12
            float4 v = *(const float4*)(src + (size_t)(bm + r) * (NNODE * HDIM)
                                            + (size_t)n * HDIM + kb + c);
            As[c + 0][r] = v.x; As[c + 1][r] = v.y;
            As[c + 2][r] = v.z; As[c + 3][r] = v.w;
        }
        // W tile: 16 rows x 64 cols
        {
            int r = tid >> 4;            // 0..15
            int c = (tid & 15) * 4;      // 0..60
            float4 v = *(const float4*)(Wn + (size_t)(k0 + r) * HDIM + bn + c);
            *(float4*)&Bs[r][c] = v;
        }
        __syncthreads();
        #pragma unroll
        for (int kk = 0; kk < BK; ++kk) {
            float4 bv = *(const float4*)&Bs[kk][tx * 4];
            float4 av = *(const float4*)&As[kk][ty * 4];
            acc[0][0] += av.x * bv.x; acc[0][1] += av.x * bv.y; acc[0][2] += av.x * bv.z; acc[0][3] += av.x * bv.w;
            acc[1][0] += av.y * bv.x; acc[1][1] += av.y * bv.y; acc[1][2] += av.y * bv.z; acc[1][3] += av.y * bv.w;
            acc[2][0] += av.z * bv.x; acc[2][1] += av.z * bv.y; acc[2][2] += av.z * bv.z; acc[2][3] += av.z * bv.w;
            acc[3][0] += av.w * bv.x; acc[3][1] += av.w * bv.y; acc[3][2] += av.w * bv.z; acc[3][3] += av.w * bv.w;
        }
        __syncthreads();
    }
    #pragma unroll
    for (int r = 0; r < 4; ++r) {
        int row = bm + ty * 4 + r;
        const float* bp = b1 + n * HDIM + bn + tx * 4;
        float4 o;
        o.x = acc[r][0] + bp[0];
        o.y = acc[r][1] + bp[1];
        o.z = acc[r][2] + bp[2];
        o.w = acc[r][3] + bp[3];
        *(float4*)(h + (size_t)row * (NNODE * HDIM) + (size_t)n * HDIM + bn + tx * 4) = o;
    }
}

// in-place LayerNorm (+g,+beta) then ReLU over rows of length 256
__global__ __launch_bounds__(256) void ln_relu_kernel(
    float* __restrict__ h, const float* __restrict__ g, const float* __restrict__ be)
{
    const int row = blockIdx.x;
    const int tid = threadIdx.x;
    float x = h[(size_t)row * HDIM + tid];
    __shared__ float red[4];

    float s = x;
    #pragma unroll
    for (int o = 32; o; o >>= 1) s += __shfl_down(s, o);
    if ((tid & 63) == 0) red[tid >> 6] = s;
    __syncthreads();
    float mu = (red[0] + red[1] + red[2] + red[3]) * (1.0f / 256.0f);
    __syncthreads();

    float d = x - mu;
    float s2 = d * d;
    #pragma unroll
    for (int o = 32; o; o >>= 1) s2 += __shfl_down(s2, o);
    if ((tid & 63) == 0) red[tid >> 6] = s2;
    __syncthreads();
    float var = (red[0] + red[1] + red[2] + red[3]) * (1.0f / 256.0f);

    float y = d * rsqrtf(var + 1e-5f) * g[tid] + be[tid];
    h[(size_t)row * HDIM + tid] = fmaxf(y, 0.0f);
}

// V = hV @ VW2 + Vb2 ; Q = V + hA @ AW2 + Ab2
__global__ __launch_bounds__(256) void mlp2_fused(
    const float* __restrict__ hV, const float* __restrict__ hA,
    const float* __restrict__ VW2, const float* __restrict__ Vb2,
    const float* __restrict__ AW2, const float* __restrict__ Ab2,
    float* __restrict__ V, float* __restrict__ Q)
{
    const int n  = blockIdx.x;
    const int bm = blockIdx.y * BM;
    const int bn = blockIdx.z * BN;   // over D
    const int tid = threadIdx.x;
    const int tx = tid & 15, ty = tid >> 4;

    __shared__ float As[BK][BM + 4];
    __shared__ float Bs[BK][BN + 4];

    float accV[4][4] = {};
    float accA[4][4] = {};

    // pass 0: hV @ VW2 -> accV ; pass 1: hA @ AW2 -> accA
    for (int pass = 0; pass < 2; ++pass) {
        const float* X  = pass ? hA : hV;
        const float* Wn = (pass ? AW2 : VW2) + (size_t)n * HDIM * DDIM;
        for (int k0 = 0; k0 < HDIM; k0 += BK) {
            {
                int r = tid >> 2, c = (tid & 3) * 4;
                float4 v = *(const float4*)(X + (size_t)(bm + r) * (NNODE * HDIM)
                                              + (size_t)n * HDIM + k0 + c);
                As[c + 0][r] = v.x; As[c + 1][r] = v.y;
                As[c + 2][r] = v.z; As[c + 3][r] = v.w;
            }
            {
                int r = tid >> 4, c = (tid & 15) * 4;
                float4 v = *(const float4*)(Wn + (size_t)(k0 + r) * DDIM + bn + c);
                *(float4*)&Bs[r][c] = v;
            }
            __syncthreads();
            if (pass == 0) {
                #pragma unroll
                for (int kk = 0; kk < BK; ++kk) {
                    float4 bv = *(const float4*)&Bs[kk][tx * 4];
                    float4 av = *(const float4*)&As[kk][ty * 4];
                    accV[0][0] += av.x * bv.x; accV[0][1] += av.x * bv.y; accV[0][2] += av.x * bv.z; accV[0][3] += av.x * bv.w;
                    accV[1][0] += av.y * bv.x; accV[1][1] += av.y * bv.y; accV[1][2] += av.y * bv.z; accV[1][3] += av.y * bv.w;
                    accV[2][0] += av.z * bv.x; accV[2][1] += av.z * bv.y; accV[2][2] += av.z * bv.z; accV[2][3] += av.z * bv.w;
                    accV[3][0] += av.w * bv.x; accV[3][1] += av.w * bv.y; accV[3][2] += av.w * bv.z; accV[3][3] += av.w * bv.w;
                }
            } else {
                #pragma unroll
                for (int kk = 0; kk < BK; ++kk) {
                    float4 bv = *(const float4*)&Bs[kk][tx * 4];
                    float4 av = *(const float4*)&As[kk][ty * 4];
                    accA[0][0] += av.x * bv.x; accA[0][1] += av.x * bv.y; accA[0][2] += av.x * bv.z; accA[0][3] += av.x * bv.w;
                    accA[1][0] += av.y * bv.x; accA[1][1] += av.y * bv.y; accA[1][2] += av.y * bv.z; accA[1][3] += av.y * bv.w;
                    accA[2][0] += av.z * bv.x; accA[2][1] += av.z * bv.y; accA[2][2] += av.z * bv.z; accA[2][3] += av.z * bv.w;
                    accA[3][0] += av.w * bv.x; accA[3][1] += av.w * bv.y; accA[3][2] += av.w * bv.z; accA[3][3] += av.w * bv.w;
                }
            }
            __syncthreads();
        }
    }

    #pragma unroll
    for (int r = 0; r < 4; ++r) {
        int row = bm + ty * 4 + r;
        const float* vb = Vb2 + n * DDIM + bn + tx * 4;
        const float* ab = Ab2 + n * DDIM + bn + tx * 4;
        float4 ov, oq;
        ov.x = accV[r][0] + vb[0]; oq.x = ov.x + accA[r][0] + ab[0];
        ov.y = accV[r][1] + vb[1]; oq.y = ov.y + accA[r][1] + ab[1];
        ov.z = accV[r][2] + vb[2]; oq.z = ov.z + accA[r][2] + ab[2];
        ov.w = accV[r][3] + vb[3]; oq.w = ov.w + accA[r][3] + ab[3];
        size_t off = (size_t)row * (NNODE * DDIM) + (size_t)n * DDIM + bn + tx * 4;
        *(float4*)(V + off) = ov;
        *(float4*)(Q + off) = oq;
    }
}

// chi for both Q and V; one block per (n, b), 128 threads = one per d
__global__ __launch_bounds__(128) void chi_kernel(
    const float* __restrict__ Q, const float* __restrict__ V,
    const int* __restrict__ le, const float* __restrict__ m1,
    const float* __restrict__ m2, float* __restrict__ out)
{
    const int n = blockIdx.x;
    const int b = blockIdx.y;
    const int tid = threadIdx.x;   // d index

    __shared__ float sm1[KNEI];
    __shared__ float sm2[KNEI * KNEI];
    __shared__ int   sidx[KNEI + 1];
    __shared__ float pq[2], pv[2];

    if (tid < KNEI) {
        float s = 0.0f;
        #pragma unroll
        for (int hh = 0; hh < 3; ++hh) s += m1[n * 24 + hh * 8 + tid];
        sm1[tid] = s;
    }
    if (tid < 64) {
        int i = tid >> 3, j = tid & 7;
        float s = 0.0f;
        if (j > i) {
            #pragma unroll
            for (int hh = 0; hh < 3; ++hh) s += m2[n * 192 + hh * 64 + tid];
        }
        sm2[tid] = s;
    }
    if (tid < KNEI + 1) sidx[tid] = le[n * 18 + tid];   // [n,0,0..8]
    __syncthreads();

    const float* Qb = Q + (size_t)b * (NNODE * DDIM);
    const float* Vb = V + (size_t)b * (NNODE * DDIM);
    const int cen = sidx[0];

    float qn[KNEI], vn[KNEI];
    #pragma unroll
    for (int k = 0; k < KNEI; ++k) {
        int nb = sidx[1 + k];
        qn[k] = Qb[nb * DDIM + tid];
        vn[k] = Vb[nb * DDIM + tid];
    }

    float sq = 0.0f, sv = 0.0f;
    #pragma unroll
    for (int k = 0; k < KNEI; ++k) { sq += sm1[k] * qn[k]; sv += sm1[k] * vn[k]; }
    #pragma unroll
    for (int i = 0; i < KNEI; ++i) {
        #pragma unroll
        for (int j = i + 1; j < KNEI; ++j) {
            float w = sm2[i * 8 + j];
            sq += w * fminf(qn[i], qn[j]);
            sv += w * fminf(vn[i], vn[j]);
        }
    }

    float valq = sq * (1.0f / 3.0f) + Qb[cen * DDIM + tid];
    float valv = sv * (1.0f / 3.0f) + Vb[cen * DDIM + tid];

    #pragma unroll
    for (int o = 32; o; o >>= 1) {
        valq += __shfl_down(valq, o);
        valv += __shfl_down(valv, o);
    }
    if ((tid & 63) == 0) { pq[tid >> 6] = valq; pv[tid >> 6] = valv; }
    __syncthreads();
    if (tid == 0) {
        out[b * NNODE + n]                = (pq[0] + pq[1]) * (1.0f / 128.0f);
        out[BCNT * NNODE + b * NNODE + n] = (pv[0] + pv[1]) * (1.0f / 128.0f);
    }
}

extern "C" void kernel_launch(void* const* d_in, const int* in_sizes, int n_in,
                              void* d_out, int out_size, void* d_ws, size_t ws_size,
                              hipStream_t stream)
{
    const float* obs  = (const float*)d_in[0];
    const float* act  = (const float*)d_in[1];
    const int*   le   = (const int*)  d_in[2];
    const float* VW1  = (const float*)d_in[3];
    const float* Vb1  = (const float*)d_in[4];
    const float* Vg1  = (const float*)d_in[5];
    const float* Vbe1 = (const float*)d_in[6];
    const float* VW2  = (const float*)d_in[7];
    const float* Vb2  = (const float*)d_in[8];
    const float* AW1  = (const float*)d_in[9];
    const float* Ab1  = (const float*)d_in[10];
    const float* Ag1  = (const float*)d_in[11];
    const float* Abe1 = (const float*)d_in[12];
    const float* AW2  = (const float*)d_in[13];
    const float* Ab2  = (const float*)d_in[14];
    const float* m1   = (const float*)d_in[15];
    const float* m2   = (const float*)d_in[16];
    float* out = (float*)d_out;

    float* hV = (float*)d_ws;                              // B*N*H = 2,097,152 f
    float* hA = hV + (size_t)BCNT * NNODE * HDIM;          // B*N*H
    float* V  = hA + (size_t)BCNT * NNODE * HDIM;          // B*N*D = 1,048,576 f
    float* Q  = V  + (size_t)BCNT * NNODE * DDIM;          // B*N*D
    // total ws use: 24 MiB

    dim3 blk(256);
    mlp1_gemm<256><<<dim3(NNODE, BCNT / BM, HDIM / BN), blk, 0, stream>>>(obs, nullptr, VW1, Vb1, hV);
    mlp1_gemm<512><<<dim3(NNODE, BCNT / BM, HDIM / BN), blk, 0, stream>>>(obs, act, AW1, Ab1, hA);
    ln_relu_kernel<<<dim3(BCNT * NNODE), blk, 0, stream>>>(hV, Vg1, Vbe1);
    ln_relu_kernel<<<dim3(BCNT * NNODE), blk, 0, stream>>>(hA, Ag1, Abe1);
    mlp2_fused<<<dim3(NNODE, BCNT / BM, DDIM / BN), blk, 0, stream>>>(hV, hA, VW2, Vb2, AW2, Ab2, V, Q);
    chi_kernel<<<dim3(NNODE, BCNT), dim3(128), 0, stream>>>(Q, V, le, m1, m2, out);
}

// Round 3
// 194.303 us; speedup vs baseline: 1.2823x; 1.2823x over previous
//
#include <hip/hip_runtime.h>
#include <hip/hip_bf16.h>

#define BCNT 128
#define NNODE 64
#define HDIM 256
#define DDIM 128
#define KNEI 8

typedef __attribute__((ext_vector_type(8))) short bf16x8;
typedef __attribute__((ext_vector_type(16))) float f32x16;

__device__ __forceinline__ unsigned short f2bf(float f) {
    union { __hip_bfloat16 b; unsigned short u; } c;
    c.b = __float2bfloat16(f);
    return c.u;
}
__device__ __forceinline__ float bf2f(unsigned short u) {
    union { unsigned short u; __hip_bfloat16 b; } c;
    c.u = u;
    return __bfloat162float(c.b);
}

// ---------------------------------------------------------------------------
// mlp1: h = X @ W1 + b1 (pre-LN), + partial LN stats.
// X = obs (KDIM=256) or concat(obs,act) (KDIM=512).
// Block: BM=64 rows x BN=64 outs, 4 waves (2m x 2o), wave = 32x32 tile.
// A (X) staged in LDS bf16 hi/lo; B (W cols) loaded global per-lane, split in reg.
// grid: (n=64, bm=2, cb=4)
// ---------------------------------------------------------------------------
template<int KDIM>
__global__ __launch_bounds__(256) void mlp1_mfma(
    const float* __restrict__ obs, const float* __restrict__ act,
    const float* __restrict__ W1, const float* __restrict__ b1,
    float* __restrict__ h, float* __restrict__ statsP)
{
    const int n   = blockIdx.x;
    const int bm  = blockIdx.y * 64;
    const int cb  = blockIdx.z;          // 0..3 col-block (64 outs)
    const int obase = cb * 64;
    const int tid = threadIdx.x;
    const int l   = tid & 63;
    const int w   = tid >> 6;            // wave 0..3
    const int wm  = w & 1;               // m-tile (32 rows)
    const int wc  = w >> 1;              // col-tile (32 outs)
    const int lo32 = l & 31, g = l >> 5;

    __shared__ __align__(16) ushort xs[2][64 * 40];  // hi/lo planes, row stride 40 ush = 80B
    __shared__ float sstat[2][64][2];

    const float* Wn = W1 + (size_t)n * KDIM * HDIM;
    const int oW = obase + wc * 32 + lo32;           // this lane's W column / out col
    const float* wp = Wn + oW;

    f32x16 acc = {};

    const int sm = tid >> 2;             // staging row 0..63
    const int sc = tid & 3;              // staging quad

    for (int k0 = 0; k0 < KDIM; k0 += 32) {
        // ---- global loads first (overlap with barrier/LDS) ----
        const float* src = obs; int kk = k0;
        if (KDIM == 512 && k0 >= 256) { src = act; kk = k0 - 256; }
        const float* xrow = src + ((size_t)(bm + sm) * NNODE + n) * HDIM + kk;
        float4 xa = *(const float4*)(xrow + sc * 4);
        float4 xb = *(const float4*)(xrow + sc * 4 + 16);

        float wv[16];
        #pragma unroll
        for (int kb = 0; kb < 2; ++kb)
            #pragma unroll
            for (int i = 0; i < 8; ++i)
                wv[kb * 8 + i] = wp[(size_t)(k0 + kb * 16 + g * 8 + i) * HDIM];

        __syncthreads();
        // ---- stage X hi/lo ----
        {
            ushort4 h4, l4;
            h4.x = f2bf(xa.x); h4.y = f2bf(xa.y); h4.z = f2bf(xa.z); h4.w = f2bf(xa.w);
            l4.x = f2bf(xa.x - bf2f(h4.x)); l4.y = f2bf(xa.y - bf2f(h4.y));
            l4.z = f2bf(xa.z - bf2f(h4.z)); l4.w = f2bf(xa.w - bf2f(h4.w));
            *(ushort4*)&xs[0][sm * 40 + sc * 4] = h4;
            *(ushort4*)&xs[1][sm * 40 + sc * 4] = l4;
            h4.x = f2bf(xb.x); h4.y = f2bf(xb.y); h4.z = f2bf(xb.z); h4.w = f2bf(xb.w);
            l4.x = f2bf(xb.x - bf2f(h4.x)); l4.y = f2bf(xb.y - bf2f(h4.y));
            l4.z = f2bf(xb.z - bf2f(h4.z)); l4.w = f2bf(xb.w - bf2f(h4.w));
            *(ushort4*)&xs[0][sm * 40 + sc * 4 + 16] = h4;
            *(ushort4*)&xs[1][sm * 40 + sc * 4 + 16] = l4;
        }
        __syncthreads();

        // ---- compute ----
        #pragma unroll
        for (int kb = 0; kb < 2; ++kb) {
            bf16x8 ahi = *(const bf16x8*)&xs[0][(wm * 32 + lo32) * 40 + kb * 16 + g * 8];
            bf16x8 alo = *(const bf16x8*)&xs[1][(wm * 32 + lo32) * 40 + kb * 16 + g * 8];
            bf16x8 bhi, blo;
            #pragma unroll
            for (int i = 0; i < 8; ++i) {
                float f = wv[kb * 8 + i];
                unsigned short hh = f2bf(f);
                bhi[i] = (short)hh;
                blo[i] = (short)f2bf(f - bf2f(hh));
            }
            acc = __builtin_amdgcn_mfma_f32_32x32x16_bf16(ahi, bhi, acc, 0, 0, 0);
            acc = __builtin_amdgcn_mfma_f32_32x32x16_bf16(ahi, blo, acc, 0, 0, 0);
            acc = __builtin_amdgcn_mfma_f32_32x32x16_bf16(alo, bhi, acc, 0, 0, 0);
        }
    }

    // ---- epilogue: bias, store pre-LN h, partial stats ----
    float bias = b1[(size_t)n * HDIM + oW];
    float hv[16];
    #pragma unroll
    for (int r = 0; r < 16; ++r) hv[r] = acc[r] + bias;

    #pragma unroll
    for (int r = 0; r < 16; ++r) {
        int mm = wm * 32 + (r & 3) + 8 * (r >> 2) + 4 * g;
        h[((size_t)(bm + mm) * NNODE + n) * HDIM + oW] = hv[r];
    }
    #pragma unroll
    for (int r = 0; r < 16; ++r) {
        float a = hv[r], q = hv[r] * hv[r];
        #pragma unroll
        for (int off = 16; off >= 1; off >>= 1) {
            a += __shfl_xor(a, off);
            q += __shfl_xor(q, off);
        }
        if (lo32 == 0) {
            int mm = wm * 32 + (r & 3) + 8 * (r >> 2) + 4 * g;
            sstat[wc][mm][0] = a;
            sstat[wc][mm][1] = q;
        }
    }
    __syncthreads();
    if (tid < 64) {
        float s1 = sstat[0][tid][0] + sstat[1][tid][0];
        float s2 = sstat[0][tid][1] + sstat[1][tid][1];
        size_t row = (size_t)(bm + tid) * NNODE + n;
        statsP[((size_t)cb * (BCNT * NNODE) + row) * 2 + 0] = s1;
        statsP[((size_t)cb * (BCNT * NNODE) + row) * 2 + 1] = s2;
    }
}

// finalize LN stats: mu, rstd per row
__global__ __launch_bounds__(256) void ln_stats(
    const float* __restrict__ statsP, float* __restrict__ mu, float* __restrict__ rstd)
{
    int i = blockIdx.x * 256 + threadIdx.x;
    if (i < BCNT * NNODE) {
        float s1 = 0.0f, s2 = 0.0f;
        #pragma unroll
        for (int cb = 0; cb < 4; ++cb) {
            s1 += statsP[((size_t)cb * (BCNT * NNODE) + i) * 2 + 0];
            s2 += statsP[((size_t)cb * (BCNT * NNODE) + i) * 2 + 1];
        }
        float m = s1 * (1.0f / 256.0f);
        float var = s2 * (1.0f / 256.0f) - m * m;
        mu[i] = m;
        rstd[i] = rsqrtf(var + 1e-5f);
    }
}

// ---------------------------------------------------------------------------
// mlp2: V = relu(ln(hV)) @ VW2 + Vb2 ; Q = V + relu(ln(hA)) @ AW2 + Ab2
// LN applied during staging. Block BM=64 x BN=64, grid (n=64, bm=2, cb=2).
// ---------------------------------------------------------------------------
__global__ __launch_bounds__(256) void mlp2_mfma(
    const float* __restrict__ hV, const float* __restrict__ hA,
    const float* __restrict__ muV, const float* __restrict__ rsV,
    const float* __restrict__ muA, const float* __restrict__ rsA,
    const float* __restrict__ Vg1, const float* __restrict__ Vbe1,
    const float* __restrict__ Ag1, const float* __restrict__ Abe1,
    const float* __restrict__ VW2, const float* __restrict__ Vb2,
    const float* __restrict__ AW2, const float* __restrict__ Ab2,
    float* __restrict__ V, float* __restrict__ Q)
{
    const int n   = blockIdx.x;
    const int bm  = blockIdx.y * 64;
    const int cb  = blockIdx.z;          // 0..1
    const int ocol = cb * 64;
    const int tid = threadIdx.x;
    const int l   = tid & 63;
    const int w   = tid >> 6;
    const int wm  = w & 1;
    const int wc  = w >> 1;
    const int lo32 = l & 31, g = l >> 5;

    __shared__ __align__(16) ushort hs[4][64 * 40]; // Vhi, Vlo, Ahi, Alo

    const float* VWn = VW2 + (size_t)n * HDIM * DDIM;
    const float* AWn = AW2 + (size_t)n * HDIM * DDIM;
    const int oW = ocol + wc * 32 + lo32;
    const float* vwp = VWn + oW;
    const float* awp = AWn + oW;

    const int sm = tid >> 2;
    const int sc = tid & 3;
    const size_t srow = (size_t)(bm + sm) * NNODE + n;
    const float muv = muV[srow], rsv = rsV[srow];
    const float mua = muA[srow], rsa = rsA[srow];

    f32x16 accV = {};
    f32x16 accA = {};

    for (int k0 = 0; k0 < HDIM; k0 += 32) {
        float4 va = *(const float4*)(hV + srow * HDIM + k0 + sc * 4);
        float4 vb = *(const float4*)(hV + srow * HDIM + k0 + sc * 4 + 16);
        float4 aa = *(const float4*)(hA + srow * HDIM + k0 + sc * 4);
        float4 ab = *(const float4*)(hA + srow * HDIM + k0 + sc * 4 + 16);
        float4 g1a = *(const float4*)(Vg1 + k0 + sc * 4);
        float4 g1b = *(const float4*)(Vg1 + k0 + sc * 4 + 16);
        float4 b1a = *(const float4*)(Vbe1 + k0 + sc * 4);
        float4 b1b = *(const float4*)(Vbe1 + k0 + sc * 4 + 16);
        float4 g2a = *(const float4*)(Ag1 + k0 + sc * 4);
        float4 g2b = *(const float4*)(Ag1 + k0 + sc * 4 + 16);
        float4 b2a = *(const float4*)(Abe1 + k0 + sc * 4);
        float4 b2b = *(const float4*)(Abe1 + k0 + sc * 4 + 16);

        float wvV[16], wvA[16];
        #pragma unroll
        for (int kb = 0; kb < 2; ++kb)
            #pragma unroll
            for (int i = 0; i < 8; ++i) {
                wvV[kb * 8 + i] = vwp[(size_t)(k0 + kb * 16 + g * 8 + i) * DDIM];
                wvA[kb * 8 + i] = awp[(size_t)(k0 + kb * 16 + g * 8 + i) * DDIM];
            }

        __syncthreads();
        {
            float y[4]; ushort4 h4, l4;
            // V plane quad a
            y[0] = fmaxf((va.x - muv) * rsv * g1a.x + b1a.x, 0.0f);
            y[1] = fmaxf((va.y - muv) * rsv * g1a.y + b1a.y, 0.0f);
            y[2] = fmaxf((va.z - muv) * rsv * g1a.z + b1a.z, 0.0f);
            y[3] = fmaxf((va.w - muv) * rsv * g1a.w + b1a.w, 0.0f);
            h4.x = f2bf(y[0]); h4.y = f2bf(y[1]); h4.z = f2bf(y[2]); h4.w = f2bf(y[3]);
            l4.x = f2bf(y[0] - bf2f(h4.x)); l4.y = f2bf(y[1] - bf2f(h4.y));
            l4.z = f2bf(y[2] - bf2f(h4.z)); l4.w = f2bf(y[3] - bf2f(h4.w));
            *(ushort4*)&hs[0][sm * 40 + sc * 4] = h4;
            *(ushort4*)&hs[1][sm * 40 + sc * 4] = l4;
            // V plane quad b
            y[0] = fmaxf((vb.x - muv) * rsv * g1b.x + b1b.x, 0.0f);
            y[1] = fmaxf((vb.y - muv) * rsv * g1b.y + b1b.y, 0.0f);
            y[2] = fmaxf((vb.z - muv) * rsv * g1b.z + b1b.z, 0.0f);
            y[3] = fmaxf((vb.w - muv) * rsv * g1b.w + b1b.w, 0.0f);
            h4.x = f2bf(y[0]); h4.y = f2bf(y[1]); h4.z = f2bf(y[2]); h4.w = f2bf(y[3]);
            l4.x = f2bf(y[0] - bf2f(h4.x)); l4.y = f2bf(y[1] - bf2f(h4.y));
            l4.z = f2bf(y[2] - bf2f(h4.z)); l4.w = f2bf(y[3] - bf2f(h4.w));
            *(ushort4*)&hs[0][sm * 40 + sc * 4 + 16] = h4;
            *(ushort4*)&hs[1][sm * 40 + sc * 4 + 16] = l4;
            // A plane quad a
            y[0] = fmaxf((aa.x - mua) * rsa * g2a.x + b2a.x, 0.0f);
            y[1] = fmaxf((aa.y - mua) * rsa * g2a.y + b2a.y, 0.0f);
            y[2] = fmaxf((aa.z - mua) * rsa * g2a.z + b2a.z, 0.0f);
            y[3] = fmaxf((aa.w - mua) * rsa * g2a.w + b2a.w, 0.0f);
            h4.x = f2bf(y[0]); h4.y = f2bf(y[1]); h4.z = f2bf(y[2]); h4.w = f2bf(y[3]);
            l4.x = f2bf(y[0] - bf2f(h4.x)); l4.y = f2bf(y[1] - bf2f(h4.y));
            l4.z = f2bf(y[2] - bf2f(h4.z)); l4.w = f2bf(y[3] - bf2f(h4.w));
            *(ushort4*)&hs[2][sm * 40 + sc * 4] = h4;
            *(ushort4*)&hs[3][sm * 40 + sc * 4] = l4;
            // A plane quad b
            y[0] = fmaxf((ab.x - mua) * rsa * g2b.x + b2b.x, 0.0f);
            y[1] = fmaxf((ab.y - mua) * rsa * g2b.y + b2b.y, 0.0f);
            y[2] = fmaxf((ab.z - mua) * rsa * g2b.z + b2b.z, 0.0f);
            y[3] = fmaxf((ab.w - mua) * rsa * g2b.w + b2b.w, 0.0f);
            h4.x = f2bf(y[0]); h4.y = f2bf(y[1]); h4.z = f2bf(y[2]); h4.w = f2bf(y[3]);
            l4.x = f2bf(y[0] - bf2f(h4.x)); l4.y = f2bf(y[1] - bf2f(h4.y));
            l4.z = f2bf(y[2] - bf2f(h4.z)); l4.w = f2bf(y[3] - bf2f(h4.w));
            *(ushort4*)&hs[2][sm * 40 + sc * 4 + 16] = h4;
            *(ushort4*)&hs[3][sm * 40 + sc * 4 + 16] = l4;
        }
        __syncthreads();

        #pragma unroll
        for (int kb = 0; kb < 2; ++kb) {
            const int aoff = (wm * 32 + lo32) * 40 + kb * 16 + g * 8;
            bf16x8 vhi = *(const bf16x8*)&hs[0][aoff];
            bf16x8 vlo = *(const bf16x8*)&hs[1][aoff];
            bf16x8 ahi = *(const bf16x8*)&hs[2][aoff];
            bf16x8 alo = *(const bf16x8*)&hs[3][aoff];
            bf16x8 bhi, blo;
            #pragma unroll
            for (int i = 0; i < 8; ++i) {
                float f = wvV[kb * 8 + i];
                unsigned short hh = f2bf(f);
                bhi[i] = (short)hh;
                blo[i] = (short)f2bf(f - bf2f(hh));
            }
            accV = __builtin_amdgcn_mfma_f32_32x32x16_bf16(vhi, bhi, accV, 0, 0, 0);
            accV = __builtin_amdgcn_mfma_f32_32x32x16_bf16(vhi, blo, accV, 0, 0, 0);
            accV = __builtin_amdgcn_mfma_f32_32x32x16_bf16(vlo, bhi, accV, 0, 0, 0);
            #pragma unroll
            for (int i = 0; i < 8; ++i) {
                float f = wvA[kb * 8 + i];
                unsigned short hh = f2bf(f);
                bhi[i] = (short)hh;
                blo[i] = (short)f2bf(f - bf2f(hh));
            }
            accA = __builtin_amdgcn_mfma_f32_32x32x16_bf16(ahi, bhi, accA, 0, 0, 0);
            accA = __builtin_amdgcn_mfma_f32_32x32x16_bf16(ahi, blo, accA, 0, 0, 0);
            accA = __builtin_amdgcn_mfma_f32_32x32x16_bf16(alo, bhi, accA, 0, 0, 0);
        }
    }

    float vb2 = Vb2[(size_t)n * DDIM + oW];
    float ab2 = Ab2[(size_t)n * DDIM + oW];
    #pragma unroll
    for (int r = 0; r < 16; ++r) {
        int mm = wm * 32 + (r & 3) + 8 * (r >> 2) + 4 * g;
        size_t off = ((size_t)(bm + mm) * NNODE + n) * DDIM + oW;
        float vv = accV[r] + vb2;
        V[off] = vv;
        Q[off] = vv + accA[r] + ab2;
    }
}

// ---------------------------------------------------------------------------
// chi for both Q and V; one block per (n, b), 128 threads = one per d
// ---------------------------------------------------------------------------
__global__ __launch_bounds__(128) void chi_kernel(
    const float* __restrict__ Q, const float* __restrict__ V,
    const int* __restrict__ le, const float* __restrict__ m1,
    const float* __restrict__ m2, float* __restrict__ out)
{
    const int n = blockIdx.x;
    const int b = blockIdx.y;
    const int tid = threadIdx.x;

    __shared__ float sm1[KNEI];
    __shared__ float sm2[KNEI * KNEI];
    __shared__ int   sidx[KNEI + 1];
    __shared__ float pq[2], pv[2];

    if (tid < KNEI) {
        float s = 0.0f;
        #pragma unroll
        for (int hh = 0; hh < 3; ++hh) s += m1[n * 24 + hh * 8 + tid];
        sm1[tid] = s;
    }
    if (tid < 64) {
        int i = tid >> 3, j = tid & 7;
        float s = 0.0f;
        if (j > i) {
            #pragma unroll
            for (int hh = 0; hh < 3; ++hh) s += m2[n * 192 + hh * 64 + tid];
        }
        sm2[tid] = s;
    }
    if (tid < KNEI + 1) sidx[tid] = le[n * 18 + tid];
    __syncthreads();

    const float* Qb = Q + (size_t)b * (NNODE * DDIM);
    const float* Vb = V + (size_t)b * (NNODE * DDIM);
    const int cen = sidx[0];

    float qn[KNEI], vn[KNEI];
    #pragma unroll
    for (int k = 0; k < KNEI; ++k) {
        int nb = sidx[1 + k];
        qn[k] = Qb[nb * DDIM + tid];
        vn[k] = Vb[nb * DDIM + tid];
    }

    float sq = 0.0f, sv = 0.0f;
    #pragma unroll
    for (int k = 0; k < KNEI; ++k) { sq += sm1[k] * qn[k]; sv += sm1[k] * vn[k]; }
    #pragma unroll
    for (int i = 0; i < KNEI; ++i) {
        #pragma unroll
        for (int j = i + 1; j < KNEI; ++j) {
            float w = sm2[i * 8 + j];
            sq += w * fminf(qn[i], qn[j]);
            sv += w * fminf(vn[i], vn[j]);
        }
    }

    float valq = sq * (1.0f / 3.0f) + Qb[cen * DDIM + tid];
    float valv = sv * (1.0f / 3.0f) + Vb[cen * DDIM + tid];

    #pragma unroll
    for (int o = 32; o; o >>= 1) {
        valq += __shfl_down(valq, o);
        valv += __shfl_down(valv, o);
    }
    if ((tid & 63) == 0) { pq[tid >> 6] = valq; pv[tid >> 6] = valv; }
    __syncthreads();
    if (tid == 0) {
        out[b * NNODE + n]                = (pq[0] + pq[1]) * (1.0f / 128.0f);
        out[BCNT * NNODE + b * NNODE + n] = (pv[0] + pv[1]) * (1.0f / 128.0f);
    }
}

extern "C" void kernel_launch(void* const* d_in, const int* in_sizes, int n_in,
                              void* d_out, int out_size, void* d_ws, size_t ws_size,
                              hipStream_t stream)
{
    const float* obs  = (const float*)d_in[0];
    const float* act  = (const float*)d_in[1];
    const int*   le   = (const int*)  d_in[2];
    const float* VW1  = (const float*)d_in[3];
    const float* Vb1  = (const float*)d_in[4];
    const float* Vg1  = (const float*)d_in[5];
    const float* Vbe1 = (const float*)d_in[6];
    const float* VW2  = (const float*)d_in[7];
    const float* Vb2  = (const float*)d_in[8];
    const float* AW1  = (const float*)d_in[9];
    const float* Ab1  = (const float*)d_in[10];
    const float* Ag1  = (const float*)d_in[11];
    const float* Abe1 = (const float*)d_in[12];
    const float* AW2  = (const float*)d_in[13];
    const float* Ab2  = (const float*)d_in[14];
    const float* m1   = (const float*)d_in[15];
    const float* m2   = (const float*)d_in[16];
    float* out = (float*)d_out;

    const size_t NR = (size_t)BCNT * NNODE;          // 8192 rows
    float* hV  = (float*)d_ws;                       // B*N*H
    float* hA  = hV + NR * HDIM;
    float* V   = hA + NR * HDIM;                     // B*N*D
    float* Q   = V + NR * DDIM;
    float* stV = Q + NR * DDIM;                      // 4*8192*2
    float* stA = stV + 4 * NR * 2;
    float* muV = stA + 4 * NR * 2;
    float* rsV = muV + NR;
    float* muA = rsV + NR;
    float* rsA = muA + NR;

    dim3 blk(256);
    mlp1_mfma<256><<<dim3(NNODE, 2, 4), blk, 0, stream>>>(obs, nullptr, VW1, Vb1, hV, stV);
    mlp1_mfma<512><<<dim3(NNODE, 2, 4), blk, 0, stream>>>(obs, act, AW1, Ab1, hA, stA);
    ln_stats<<<dim3(32), blk, 0, stream>>>(stV, muV, rsV);
    ln_stats<<<dim3(32), blk, 0, stream>>>(stA, muA, rsA);
    mlp2_mfma<<<dim3(NNODE, 2, 2), blk, 0, stream>>>(hV, hA, muV, rsV, muA, rsA,
                                                     Vg1, Vbe1, Ag1, Abe1,
                                                     VW2, Vb2, AW2, Ab2, V, Q);
    chi_kernel<<<dim3(NNODE, BCNT), dim3(128), 0, stream>>>(Q, V, le, m1, m2, out);
}